// Round 14
// baseline (134.373 us; speedup 1.0000x reference)
//
#include <hip/hip_runtime.h>
#include <hip/hip_bf16.h>
#include <math.h>

typedef __bf16 bf16x8 __attribute__((ext_vector_type(8)));
typedef float  f32x4  __attribute__((ext_vector_type(4)));
typedef unsigned int u32;
typedef u32 u32x4 __attribute__((ext_vector_type(4)));
typedef unsigned short u16;

// Staged W (bf16, MFMA-fragment chunk order) lives in the FIRST 256 KB of
// d_out (overwritten by broadcast_out afterwards).
#define WS_UQ    0       // 256 f32
#define WS_UK    256     // 256 f32
#define WS_CONST 512     // [0]=dq [1]=dk [2]=mlp2_b
#define WS_SQ    528     // 16384 f32
#define WS_SK    16912   // 16384 f32

__device__ __forceinline__ float elu1(float x) {
    return x > 0.f ? x : (__expf(x) - 1.f);
}

// ---------------------------------------------------------------------------
__global__ void prep_all(const float* __restrict__ w1, const float* __restrict__ w2,
                         const float* __restrict__ bn_g, const float* __restrict__ bn_b,
                         const float* __restrict__ bn_mean, const float* __restrict__ bn_var,
                         const float* __restrict__ wq_w, const float* __restrict__ wq_b,
                         const float* __restrict__ wk_w, const float* __restrict__ wk_b,
                         const float* __restrict__ mlp2_w, const float* __restrict__ mlp2_b,
                         float* __restrict__ ws, float* __restrict__ outb) {
    if (blockIdx.x == 0) {
        __shared__ float redq[256], redk[256];
        const int h = threadIdx.x;
        float s  = bn_g[h] * rsqrtf(bn_var[h] + 1e-5f);
        float tt = bn_b[h] - bn_mean[h] * s;
        float vq = 0.f, vk = 0.f;
        #pragma unroll
        for (int d = 0; d < 64; ++d) {
            vq += wq_w[d * 256 + h] * mlp2_w[64 + d];  // wq_half = mlp2_w[0, D:]
            vk += wk_w[d * 256 + h] * mlp2_w[d];       // wk_half = mlp2_w[0, :D]
        }
        ws[WS_UQ + h] = s * vq;
        ws[WS_UK + h] = s * vk;
        redq[h] = tt * vq;
        redk[h] = tt * vk;
        __syncthreads();
        for (int st = 128; st > 0; st >>= 1) {
            if (h < st) { redq[h] += redq[h + st]; redk[h] += redk[h + st]; }
            __syncthreads();
        }
        if (h == 0) {
            float cq = 0.f, ck = 0.f;
            for (int d = 0; d < 64; ++d) {
                cq += wq_b[d] * mlp2_w[64 + d];
                ck += wk_b[d] * mlp2_w[d];
            }
            ws[WS_CONST + 0] = redq[0] + cq;
            ws[WS_CONST + 1] = redk[0] + ck;
            ws[WS_CONST + 2] = mlp2_b[0];
        }
        return;
    }
    const int bid = blockIdx.x - 1;
    const int m   = bid >> 3;
    const int kt  = bid & 7;
    const float* src = m ? w2 : w1;
    __bf16* stg = (__bf16*)outb + m * 65536;
    const int tid = threadIdx.x;
    #pragma unroll
    for (int it = 0; it < 4; ++it) {
        int idx = it * 256 + tid;          // 0..1023 = nt*64 + l
        int nt = idx >> 6, l = idx & 63;
        int lr = l & 15, lk = l >> 4;
        const float* sp = src + (nt * 16 + lr) * 256 + kt * 32 + lk * 8;
        bf16x8 hi;
        #pragma unroll
        for (int j = 0; j < 8; ++j) hi[j] = (__bf16)sp[j];
        *(bf16x8*)(stg + (kt * 16 + nt) * 512 + l * 8) = hi;
    }
}

// ---------------------------------------------------------------------------
// R13 main (byte-identical): 512 blocks x 256 thr, 32 rows/block, W read
// once per block per phase, rotation prefetch, no staging barriers.
// ---------------------------------------------------------------------------
__global__ __launch_bounds__(256) void main_mfma(const float* __restrict__ inp,
                                                 const float* __restrict__ b1,
                                                 const float* __restrict__ b2,
                                                 float* __restrict__ ws,
                                                 const float* __restrict__ outb) {
    __shared__ u32 X1p[8192];        // 32KB
    __shared__ float redq[128], redk[128];

    const int tid = threadIdx.x;
    const int l   = tid & 63;
    const int w   = tid >> 6;
    const int lr  = l & 15;
    const int lk  = l >> 4;
    const int rows0 = blockIdx.x * 32;
    const int n0  = w * 64;

    const __bf16* s1 = (const __bf16*)outb;
    const __bf16* s2 = s1 + 65536;
    const float* arow0 = inp + (size_t)(rows0 + lr) * 256 + lk * 8;
    const float* arow1 = inp + (size_t)(rows0 + 16 + lr) * 256 + lk * 8;

    f32x4 acc[2][4];

    #pragma unroll
    for (int p = 0; p < 2; ++p)
        #pragma unroll
        for (int nt = 0; nt < 4; ++nt) acc[p][nt] = (f32x4)0.f;

    bf16x8 bc[4];
    float4 fa0, fa1, fb0, fb1;
    #pragma unroll
    for (int nt = 0; nt < 4; ++nt)
        bc[nt] = *(const bf16x8*)(s1 + ((0 * 16 + w * 4 + nt) << 9) + l * 8);
    fa0 = ((const float4*)arow0)[0];
    fa1 = ((const float4*)arow0)[1];
    fb0 = ((const float4*)arow1)[0];
    fb1 = ((const float4*)arow1)[1];

    #pragma unroll
    for (int kt = 0; kt < 8; ++kt) {
        bf16x8 bn[4];
        float4 ga0 = fa0, ga1 = fa1, gb0 = fb0, gb1 = fb1;
        if (kt < 7) {
            #pragma unroll
            for (int nt = 0; nt < 4; ++nt)
                bn[nt] = *(const bf16x8*)(s1 + (((kt + 1) * 16 + w * 4 + nt) << 9) + l * 8);
            ga0 = ((const float4*)(arow0 + (kt + 1) * 32))[0];
            ga1 = ((const float4*)(arow0 + (kt + 1) * 32))[1];
            gb0 = ((const float4*)(arow1 + (kt + 1) * 32))[0];
            gb1 = ((const float4*)(arow1 + (kt + 1) * 32))[1];
        } else {
            #pragma unroll
            for (int nt = 0; nt < 4; ++nt) bn[nt] = bc[nt];
        }
        bf16x8 ah[2], al[2];
        {
            float fv0[8] = {fa0.x,fa0.y,fa0.z,fa0.w,fa1.x,fa1.y,fa1.z,fa1.w};
            float fv1[8] = {fb0.x,fb0.y,fb0.z,fb0.w,fb1.x,fb1.y,fb1.z,fb1.w};
            #pragma unroll
            for (int j = 0; j < 8; ++j) {
                __bf16 h0 = (__bf16)fv0[j];
                ah[0][j] = h0; al[0][j] = (__bf16)(fv0[j] - (float)h0);
                __bf16 h1 = (__bf16)fv1[j];
                ah[1][j] = h1; al[1][j] = (__bf16)(fv1[j] - (float)h1);
            }
        }
        #pragma unroll
        for (int p = 0; p < 2; ++p)
            #pragma unroll
            for (int nt = 0; nt < 4; ++nt) {
                acc[p][nt] = __builtin_amdgcn_mfma_f32_16x16x32_bf16(ah[p], bc[nt], acc[p][nt], 0, 0, 0);
                acc[p][nt] = __builtin_amdgcn_mfma_f32_16x16x32_bf16(al[p], bc[nt], acc[p][nt], 0, 0, 0);
            }
        #pragma unroll
        for (int nt = 0; nt < 4; ++nt) bc[nt] = bn[nt];
        fa0 = ga0; fa1 = ga1; fb0 = gb0; fb1 = gb1;
    }
    #pragma unroll
    for (int p = 0; p < 2; ++p)
        #pragma unroll
        for (int nt = 0; nt < 4; ++nt) {
            int col = n0 + nt * 16 + lr;
            float bb = b1[col];
            #pragma unroll
            for (int r = 0; r < 4; ++r) {
                int row = p * 16 + lk * 4 + r;
                float v = elu1(acc[p][nt][r] + bb);
                __bf16 hv = (__bf16)v;
                __bf16 lv = (__bf16)(v - (float)hv);
                u32 pk = ((u32)__builtin_bit_cast(u16, hv) << 16) | __builtin_bit_cast(u16, lv);
                int ob = row * 1024 + ((col * 4) ^ ((row & 15) << 4));
                *(u32*)((char*)X1p + ob) = pk;
            }
        }
    __syncthreads();

    #pragma unroll
    for (int p = 0; p < 2; ++p)
        #pragma unroll
        for (int nt = 0; nt < 4; ++nt) acc[p][nt] = (f32x4)0.f;

    const int sw = lr << 4;

    bf16x8 bc2[4];
    #pragma unroll
    for (int nt = 0; nt < 4; ++nt)
        bc2[nt] = *(const bf16x8*)(s2 + ((0 * 16 + w * 4 + nt) << 9) + l * 8);

    #pragma unroll
    for (int kt = 0; kt < 8; ++kt) {
        bf16x8 bn[4];
        if (kt < 7) {
            #pragma unroll
            for (int nt = 0; nt < 4; ++nt)
                bn[nt] = *(const bf16x8*)(s2 + (((kt + 1) * 16 + w * 4 + nt) << 9) + l * 8);
        } else {
            #pragma unroll
            for (int nt = 0; nt < 4; ++nt) bn[nt] = bc2[nt];
        }
        int cb = kt * 128 + lk * 32;
        bf16x8 ah[2], al[2];
        #pragma unroll
        for (int p = 0; p < 2; ++p) {
            int base = (p * 16 + lr) * 1024;
            u32x4 q0 = *(const u32x4*)((const char*)X1p + base + (cb ^ sw));
            u32x4 q1 = *(const u32x4*)((const char*)X1p + base + ((cb + 16) ^ sw));
            u32 hw0 = __builtin_amdgcn_perm(q0.y, q0.x, 0x07060302u);
            u32 hw1 = __builtin_amdgcn_perm(q0.w, q0.z, 0x07060302u);
            u32 hw2 = __builtin_amdgcn_perm(q1.y, q1.x, 0x07060302u);
            u32 hw3 = __builtin_amdgcn_perm(q1.w, q1.z, 0x07060302u);
            u32 lw0 = __builtin_amdgcn_perm(q0.y, q0.x, 0x05040100u);
            u32 lw1 = __builtin_amdgcn_perm(q0.w, q0.z, 0x05040100u);
            u32 lw2 = __builtin_amdgcn_perm(q1.y, q1.x, 0x05040100u);
            u32 lw3 = __builtin_amdgcn_perm(q1.w, q1.z, 0x05040100u);
            u32x4 hh = {hw0, hw1, hw2, hw3};
            u32x4 ll = {lw0, lw1, lw2, lw3};
            ah[p] = __builtin_bit_cast(bf16x8, hh);
            al[p] = __builtin_bit_cast(bf16x8, ll);
        }
        #pragma unroll
        for (int p = 0; p < 2; ++p)
            #pragma unroll
            for (int nt = 0; nt < 4; ++nt) {
                acc[p][nt] = __builtin_amdgcn_mfma_f32_16x16x32_bf16(ah[p], bc2[nt], acc[p][nt], 0, 0, 0);
                acc[p][nt] = __builtin_amdgcn_mfma_f32_16x16x32_bf16(al[p], bc2[nt], acc[p][nt], 0, 0, 0);
            }
        #pragma unroll
        for (int nt = 0; nt < 4; ++nt) bc2[nt] = bn[nt];
    }

    float sqp[2][4] = {{0.f,0.f,0.f,0.f},{0.f,0.f,0.f,0.f}};
    float skp[2][4] = {{0.f,0.f,0.f,0.f},{0.f,0.f,0.f,0.f}};
    const float* uq = ws + WS_UQ;
    const float* uk = ws + WS_UK;
    #pragma unroll
    for (int p = 0; p < 2; ++p)
        #pragma unroll
        for (int nt = 0; nt < 4; ++nt) {
            int col = n0 + nt * 16 + lr;
            float bb = b2[col], qc = uq[col], kc = uk[col];
            #pragma unroll
            for (int r = 0; r < 4; ++r) {
                float v = elu1(acc[p][nt][r] + bb);
                sqp[p][r] += v * qc;
                skp[p][r] += v * kc;
            }
        }
    #pragma unroll
    for (int mm = 8; mm >= 1; mm >>= 1) {
        #pragma unroll
        for (int p = 0; p < 2; ++p)
            #pragma unroll
            for (int r = 0; r < 4; ++r) {
                sqp[p][r] += __shfl_xor(sqp[p][r], mm);
                skp[p][r] += __shfl_xor(skp[p][r], mm);
            }
    }
    if (lr == 0) {
        #pragma unroll
        for (int p = 0; p < 2; ++p)
            #pragma unroll
            for (int r = 0; r < 4; ++r) {
                int row = p * 16 + lk * 4 + r;
                redq[w * 32 + row] = sqp[p][r];
                redk[w * 32 + row] = skp[p][r];
            }
    }
    __syncthreads();
    if (tid < 32) {
        float s = ws[WS_CONST + 0];
        #pragma unroll
        for (int ww = 0; ww < 4; ++ww) s += redq[ww * 32 + tid];
        ws[WS_SQ + rows0 + tid] = s;
    } else if (tid < 64) {
        int rl = tid - 32;
        float s = ws[WS_CONST + 1];
        #pragma unroll
        for (int ww = 0; ww < 4; ++ww) s += redk[ww * 32 + rl];
        ws[WS_SK + rows0 + rl] = s;
    }
}

// ---------------------------------------------------------------------------
// R9-proven broadcast.  IDEMPOTENT (reads ws only) -> launched 5x in R14 to
// measure t_broadcast: (dur - 50.4)/4 = t_bc + gap.
// ---------------------------------------------------------------------------
__global__ __launch_bounds__(256) void broadcast_out(const float* __restrict__ ws,
                                                     float* __restrict__ out) {
    __shared__ float skL[2048];
    const int bi = blockIdx.x;
    const int b = bi >> 8;
    const int chunk = bi & 255;
    const int tid = threadIdx.x;

    float4* skL4 = (float4*)skL;
    const float4* skb4 = (const float4*)(ws + WS_SK + b * 2048);
    #pragma unroll
    for (int it = 0; it < 2; ++it) skL4[it * 256 + tid] = skb4[it * 256 + tid];
    __syncthreads();

    const float mb = ws[WS_CONST + 2];
    const int i0 = chunk * 8;
    #pragma unroll
    for (int i = 0; i < 8; ++i) {
        float sval = ws[WS_SQ + b * 2048 + i0 + i] + mb;
        float4* orow = (float4*)(out + ((size_t)(b * 2048 + i0 + i)) * 2048);
        #pragma unroll
        for (int hh = 0; hh < 2; ++hh) {
            int j4 = hh * 256 + tid;
            float4 v = skL4[j4];
            orow[j4] = make_float4(sval + v.x, sval + v.y, sval + v.z, sval + v.w);
        }
    }
}

// ---------------------------------------------------------------------------
extern "C" void kernel_launch(void* const* d_in, const int* in_sizes, int n_in,
                              void* d_out, int out_size, void* d_ws, size_t ws_size,
                              hipStream_t stream) {
    const float* inputs  = (const float*)d_in[0];
    const float* fc1_w   = (const float*)d_in[1];
    const float* fc1_b   = (const float*)d_in[2];
    const float* fc2_w   = (const float*)d_in[3];
    const float* fc2_b   = (const float*)d_in[4];
    const float* bn_g    = (const float*)d_in[5];
    const float* bn_b    = (const float*)d_in[6];
    const float* bn_mean = (const float*)d_in[7];
    const float* bn_var  = (const float*)d_in[8];
    const float* wq_w    = (const float*)d_in[9];
    const float* wq_b    = (const float*)d_in[10];
    const float* wk_w    = (const float*)d_in[11];
    const float* wk_b    = (const float*)d_in[12];
    const float* mlp2_w  = (const float*)d_in[13];
    const float* mlp2_b  = (const float*)d_in[14];
    float* ws  = (float*)d_ws;
    float* out = (float*)d_out;

    hipLaunchKernelGGL(prep_all, dim3(17), dim3(256), 0, stream,
                       fc1_w, fc2_w, bn_g, bn_b, bn_mean, bn_var,
                       wq_w, wq_b, wk_w, wk_b, mlp2_w, mlp2_b, ws, out);
    hipLaunchKernelGGL(main_mfma, dim3(512), dim3(256), 0, stream,
                       inputs, fc1_b, fc2_b, ws, out);
    hipLaunchKernelGGL(broadcast_out, dim3(2048), dim3(256), 0, stream, ws, out);
    hipLaunchKernelGGL(broadcast_out, dim3(2048), dim3(256), 0, stream, ws, out);
    hipLaunchKernelGGL(broadcast_out, dim3(2048), dim3(256), 0, stream, ws, out);
    hipLaunchKernelGGL(broadcast_out, dim3(2048), dim3(256), 0, stream, ws, out);
    hipLaunchKernelGGL(broadcast_out, dim3(2048), dim3(256), 0, stream, ws, out);
}

// Round 15
// 47.215 us; speedup vs baseline: 2.8460x; 2.8460x over previous
//
#include <hip/hip_runtime.h>
#include <hip/hip_bf16.h>
#include <math.h>

typedef __bf16 bf16x8 __attribute__((ext_vector_type(8)));
typedef float  f32x4  __attribute__((ext_vector_type(4)));
typedef unsigned int u32;
typedef u32 u32x4 __attribute__((ext_vector_type(4)));
typedef unsigned short u16;

// Staged W (bf16, MFMA-fragment chunk order) lives in the FIRST 256 KB of
// d_out (overwritten by broadcast_out afterwards).
#define WS_UQ    0       // 256 f32
#define WS_UK    256     // 256 f32
#define WS_CONST 512     // [0]=dq [1]=dk [2]=mlp2_b
#define WS_SQ    528     // 16384 f32
#define WS_SK    16912   // 16384 f32

__device__ __forceinline__ float elu1(float x) {
    return x > 0.f ? x : (__expf(x) - 1.f);
}

__device__ __forceinline__ void gload16(const void* g, void* l) {
    __builtin_amdgcn_global_load_lds((const __attribute__((address_space(1))) void*)g,
                                     (__attribute__((address_space(3))) void*)l,
                                     16, 0, 0);
}

// ---------------------------------------------------------------------------
// block 0: fold BN + Q/K + final dot into uq/uk, dq/dk (-> ws).
// blocks 1..16: W1/W2 -> bf16 fragment-chunk order (-> out scratch).
// ---------------------------------------------------------------------------
__global__ void prep_all(const float* __restrict__ w1, const float* __restrict__ w2,
                         const float* __restrict__ bn_g, const float* __restrict__ bn_b,
                         const float* __restrict__ bn_mean, const float* __restrict__ bn_var,
                         const float* __restrict__ wq_w, const float* __restrict__ wq_b,
                         const float* __restrict__ wk_w, const float* __restrict__ wk_b,
                         const float* __restrict__ mlp2_w, const float* __restrict__ mlp2_b,
                         float* __restrict__ ws, float* __restrict__ outb) {
    if (blockIdx.x == 0) {
        __shared__ float redq[256], redk[256];
        const int h = threadIdx.x;
        float s  = bn_g[h] * rsqrtf(bn_var[h] + 1e-5f);
        float tt = bn_b[h] - bn_mean[h] * s;
        float vq = 0.f, vk = 0.f;
        #pragma unroll
        for (int d = 0; d < 64; ++d) {
            vq += wq_w[d * 256 + h] * mlp2_w[64 + d];  // wq_half = mlp2_w[0, D:]
            vk += wk_w[d * 256 + h] * mlp2_w[d];       // wk_half = mlp2_w[0, :D]
        }
        ws[WS_UQ + h] = s * vq;
        ws[WS_UK + h] = s * vk;
        redq[h] = tt * vq;
        redk[h] = tt * vk;
        __syncthreads();
        for (int st = 128; st > 0; st >>= 1) {
            if (h < st) { redq[h] += redq[h + st]; redk[h] += redk[h + st]; }
            __syncthreads();
        }
        if (h == 0) {
            float cq = 0.f, ck = 0.f;
            for (int d = 0; d < 64; ++d) {
                cq += wq_b[d] * mlp2_w[64 + d];
                ck += wk_b[d] * mlp2_w[d];
            }
            ws[WS_CONST + 0] = redq[0] + cq;
            ws[WS_CONST + 1] = redk[0] + ck;
            ws[WS_CONST + 2] = mlp2_b[0];
        }
        return;
    }
    const int bid = blockIdx.x - 1;
    const int m   = bid >> 3;
    const int kt  = bid & 7;
    const float* src = m ? w2 : w1;
    __bf16* stg = (__bf16*)outb + m * 65536;
    const int tid = threadIdx.x;
    #pragma unroll
    for (int it = 0; it < 4; ++it) {
        int idx = it * 256 + tid;          // 0..1023 = nt*64 + l
        int nt = idx >> 6, l = idx & 63;
        int lr = l & 15, lk = l >> 4;
        const float* sp = src + (nt * 16 + lr) * 256 + kt * 32 + lk * 8;
        bf16x8 hi;
        #pragma unroll
        for (int j = 0; j < 8; ++j) hi[j] = (__bf16)sp[j];
        *(bf16x8*)(stg + (kt * 16 + nt) * 512 + l * 8) = hi;
    }
}

// ---------------------------------------------------------------------------
// Fused 2-layer MLP, 2-term split-bf16 MFMA.  512 blocks x 256 thr (4 waves),
// 32 rows/block.  NEW vs R13: the block's whole A-tile (32 KB f32) is staged
// into LDS up-front via global_load_lds w=16 (linear dest + pre-swizzled
// per-lane global source), so phase 1's kt loop has ZERO HBM dependency --
// A-frags come from conflict-free swizzled ds_read_b128.  The same 32 KB LDS
// is reused for the packed-X1 handoff after a barrier.
// lane: lr=l&15 lk=l>>4.  frags: A[lr][kt*32+lk*8+j], B[n=lr][kt*32+lk*8+j],
// D: row=lk*4+r, col=lr.  Swizzle: byte ^= ((row&15)<<4) within each 1KB row.
// ---------------------------------------------------------------------------
__global__ __launch_bounds__(256) void main_mfma(const float* __restrict__ inp,
                                                 const float* __restrict__ b1,
                                                 const float* __restrict__ b2,
                                                 float* __restrict__ ws,
                                                 const float* __restrict__ outb) {
    __shared__ u32 LDSu[8192];       // 32KB: phase1 = A f32 (swizzled); then X1p
    __shared__ float redq[128], redk[128];

    const int tid = threadIdx.x;
    const int l   = tid & 63;
    const int w   = tid >> 6;        // 0..3: n-slice
    const int lr  = l & 15;
    const int lk  = l >> 4;
    const int rows0 = blockIdx.x * 32;
    const int n0  = w * 64;

    const __bf16* s1 = (const __bf16*)outb;
    const __bf16* s2 = s1 + 65536;

    // ---- stage A-tile: 32 rows x 1KB, swizzled image, 8 gload16 per thread
    {
        const char* inb = (const char*)(inp + (size_t)rows0 * 256);
        #pragma unroll
        for (int j = 0; j < 8; ++j) {
            int row = w * 8 + j;
            int srcb = row * 1024 + ((l * 16) ^ ((row & 15) << 4));
            gload16(inb + srcb, ((char*)LDSu) + row * 1024 + l * 16);
        }
    }

    f32x4 acc[2][4];
    #pragma unroll
    for (int p = 0; p < 2; ++p)
        #pragma unroll
        for (int nt = 0; nt < 4; ++nt) acc[p][nt] = (f32x4)0.f;

    // B kt=0 prefetch (in flight across the staging barrier)
    bf16x8 bc[4];
    #pragma unroll
    for (int nt = 0; nt < 4; ++nt)
        bc[nt] = *(const bf16x8*)(s1 + ((0 * 16 + w * 4 + nt) << 9) + l * 8);

    __syncthreads();                 // drains gload_lds; A visible

    const int sw = lr << 4;          // (row & 15) == lr for rows p*16+lr

    // ================= phase 1: x1 = elu(A @ W1^T + b1) =================
    #pragma unroll
    for (int kt = 0; kt < 8; ++kt) {
        bf16x8 bn[4];
        if (kt < 7) {
            #pragma unroll
            for (int nt = 0; nt < 4; ++nt)
                bn[nt] = *(const bf16x8*)(s1 + (((kt + 1) * 16 + w * 4 + nt) << 9) + l * 8);
        } else {
            #pragma unroll
            for (int nt = 0; nt < 4; ++nt) bn[nt] = bc[nt];
        }
        int cb = kt * 128 + lk * 32;
        bf16x8 ah[2], al[2];
        #pragma unroll
        for (int p = 0; p < 2; ++p) {
            int base = (p * 16 + lr) * 1024;
            float4 f0 = *(const float4*)((const char*)LDSu + base + (cb ^ sw));
            float4 f1 = *(const float4*)((const char*)LDSu + base + ((cb + 16) ^ sw));
            float fv[8] = {f0.x,f0.y,f0.z,f0.w,f1.x,f1.y,f1.z,f1.w};
            #pragma unroll
            for (int j = 0; j < 8; ++j) {
                __bf16 hv = (__bf16)fv[j];
                ah[p][j] = hv;
                al[p][j] = (__bf16)(fv[j] - (float)hv);
            }
        }
        #pragma unroll
        for (int p = 0; p < 2; ++p)
            #pragma unroll
            for (int nt = 0; nt < 4; ++nt) {
                acc[p][nt] = __builtin_amdgcn_mfma_f32_16x16x32_bf16(ah[p], bc[nt], acc[p][nt], 0, 0, 0);
                acc[p][nt] = __builtin_amdgcn_mfma_f32_16x16x32_bf16(al[p], bc[nt], acc[p][nt], 0, 0, 0);
            }
        #pragma unroll
        for (int nt = 0; nt < 4; ++nt) bc[nt] = bn[nt];
    }

    __syncthreads();                 // all waves done reading A from LDSu

    // epilogue 1: bias + elu -> packed bf16 hi|lo into LDSu (X1p, swizzled)
    #pragma unroll
    for (int p = 0; p < 2; ++p)
        #pragma unroll
        for (int nt = 0; nt < 4; ++nt) {
            int col = n0 + nt * 16 + lr;
            float bb = b1[col];
            #pragma unroll
            for (int r = 0; r < 4; ++r) {
                int row = p * 16 + lk * 4 + r;
                float v = elu1(acc[p][nt][r] + bb);
                __bf16 hv = (__bf16)v;
                __bf16 lv = (__bf16)(v - (float)hv);
                u32 pk = ((u32)__builtin_bit_cast(u16, hv) << 16) | __builtin_bit_cast(u16, lv);
                int ob = row * 1024 + ((col * 4) ^ ((row & 15) << 4));
                *(u32*)((char*)LDSu + ob) = pk;
            }
        }
    __syncthreads();

    // ================= phase 2: z2 = x1 @ W2^T + b2 =================
    #pragma unroll
    for (int p = 0; p < 2; ++p)
        #pragma unroll
        for (int nt = 0; nt < 4; ++nt) acc[p][nt] = (f32x4)0.f;

    bf16x8 bc2[4];
    #pragma unroll
    for (int nt = 0; nt < 4; ++nt)
        bc2[nt] = *(const bf16x8*)(s2 + ((0 * 16 + w * 4 + nt) << 9) + l * 8);

    #pragma unroll
    for (int kt = 0; kt < 8; ++kt) {
        bf16x8 bn[4];
        if (kt < 7) {
            #pragma unroll
            for (int nt = 0; nt < 4; ++nt)
                bn[nt] = *(const bf16x8*)(s2 + (((kt + 1) * 16 + w * 4 + nt) << 9) + l * 8);
        } else {
            #pragma unroll
            for (int nt = 0; nt < 4; ++nt) bn[nt] = bc2[nt];
        }
        int cb = kt * 128 + lk * 32;
        bf16x8 ah[2], al[2];
        #pragma unroll
        for (int p = 0; p < 2; ++p) {
            int base = (p * 16 + lr) * 1024;
            u32x4 q0 = *(const u32x4*)((const char*)LDSu + base + (cb ^ sw));
            u32x4 q1 = *(const u32x4*)((const char*)LDSu + base + ((cb + 16) ^ sw));
            u32 hw0 = __builtin_amdgcn_perm(q0.y, q0.x, 0x07060302u);
            u32 hw1 = __builtin_amdgcn_perm(q0.w, q0.z, 0x07060302u);
            u32 hw2 = __builtin_amdgcn_perm(q1.y, q1.x, 0x07060302u);
            u32 hw3 = __builtin_amdgcn_perm(q1.w, q1.z, 0x07060302u);
            u32 lw0 = __builtin_amdgcn_perm(q0.y, q0.x, 0x05040100u);
            u32 lw1 = __builtin_amdgcn_perm(q0.w, q0.z, 0x05040100u);
            u32 lw2 = __builtin_amdgcn_perm(q1.y, q1.x, 0x05040100u);
            u32 lw3 = __builtin_amdgcn_perm(q1.w, q1.z, 0x05040100u);
            u32x4 hh = {hw0, hw1, hw2, hw3};
            u32x4 ll = {lw0, lw1, lw2, lw3};
            ah[p] = __builtin_bit_cast(bf16x8, hh);
            al[p] = __builtin_bit_cast(bf16x8, ll);
        }
        #pragma unroll
        for (int p = 0; p < 2; ++p)
            #pragma unroll
            for (int nt = 0; nt < 4; ++nt) {
                acc[p][nt] = __builtin_amdgcn_mfma_f32_16x16x32_bf16(ah[p], bc2[nt], acc[p][nt], 0, 0, 0);
                acc[p][nt] = __builtin_amdgcn_mfma_f32_16x16x32_bf16(al[p], bc2[nt], acc[p][nt], 0, 0, 0);
            }
        #pragma unroll
        for (int nt = 0; nt < 4; ++nt) bc2[nt] = bn[nt];
    }

    // epilogue 2: bias + elu, dot with uq/uk, reduce over lanes then waves
    float sqp[2][4] = {{0.f,0.f,0.f,0.f},{0.f,0.f,0.f,0.f}};
    float skp[2][4] = {{0.f,0.f,0.f,0.f},{0.f,0.f,0.f,0.f}};
    const float* uq = ws + WS_UQ;
    const float* uk = ws + WS_UK;
    #pragma unroll
    for (int p = 0; p < 2; ++p)
        #pragma unroll
        for (int nt = 0; nt < 4; ++nt) {
            int col = n0 + nt * 16 + lr;
            float bb = b2[col], qc = uq[col], kc = uk[col];
            #pragma unroll
            for (int r = 0; r < 4; ++r) {
                float v = elu1(acc[p][nt][r] + bb);
                sqp[p][r] += v * qc;
                skp[p][r] += v * kc;
            }
        }
    #pragma unroll
    for (int mm = 8; mm >= 1; mm >>= 1) {   // reduce over lr (16-lane groups)
        #pragma unroll
        for (int p = 0; p < 2; ++p)
            #pragma unroll
            for (int r = 0; r < 4; ++r) {
                sqp[p][r] += __shfl_xor(sqp[p][r], mm);
                skp[p][r] += __shfl_xor(skp[p][r], mm);
            }
    }
    if (lr == 0) {
        #pragma unroll
        for (int p = 0; p < 2; ++p)
            #pragma unroll
            for (int r = 0; r < 4; ++r) {
                int row = p * 16 + lk * 4 + r;
                redq[w * 32 + row] = sqp[p][r];
                redk[w * 32 + row] = skp[p][r];
            }
    }
    __syncthreads();
    if (tid < 32) {
        float s = ws[WS_CONST + 0];
        #pragma unroll
        for (int ww = 0; ww < 4; ++ww) s += redq[ww * 32 + tid];
        ws[WS_SQ + rows0 + tid] = s;
    } else if (tid < 64) {
        int rl = tid - 32;
        float s = ws[WS_CONST + 1];
        #pragma unroll
        for (int ww = 0; ww < 4; ++ww) s += redk[ww * 32 + rl];
        ws[WS_SK + rows0 + rl] = s;
    }
}

// ---------------------------------------------------------------------------
// probs[b,i,j] = sq[b,i] + sk[b,j] + mb   (R9-proven form, at BW floor)
// ---------------------------------------------------------------------------
__global__ __launch_bounds__(256) void broadcast_out(const float* __restrict__ ws,
                                                     float* __restrict__ out) {
    __shared__ float skL[2048];
    const int bi = blockIdx.x;
    const int b = bi >> 8;
    const int chunk = bi & 255;
    const int tid = threadIdx.x;

    float4* skL4 = (float4*)skL;
    const float4* skb4 = (const float4*)(ws + WS_SK + b * 2048);
    #pragma unroll
    for (int it = 0; it < 2; ++it) skL4[it * 256 + tid] = skb4[it * 256 + tid];
    __syncthreads();

    const float mb = ws[WS_CONST + 2];
    const int i0 = chunk * 8;
    #pragma unroll
    for (int i = 0; i < 8; ++i) {
        float sval = ws[WS_SQ + b * 2048 + i0 + i] + mb;
        float4* orow = (float4*)(out + ((size_t)(b * 2048 + i0 + i)) * 2048);
        #pragma unroll
        for (int hh = 0; hh < 2; ++hh) {
            int j4 = hh * 256 + tid;
            float4 v = skL4[j4];
            orow[j4] = make_float4(sval + v.x, sval + v.y, sval + v.z, sval + v.w);
        }
    }
}

// ---------------------------------------------------------------------------
extern "C" void kernel_launch(void* const* d_in, const int* in_sizes, int n_in,
                              void* d_out, int out_size, void* d_ws, size_t ws_size,
                              hipStream_t stream) {
    const float* inputs  = (const float*)d_in[0];
    const float* fc1_w   = (const float*)d_in[1];
    const float* fc1_b   = (const float*)d_in[2];
    const float* fc2_w   = (const float*)d_in[3];
    const float* fc2_b   = (const float*)d_in[4];
    const float* bn_g    = (const float*)d_in[5];
    const float* bn_b    = (const float*)d_in[6];
    const float* bn_mean = (const float*)d_in[7];
    const float* bn_var  = (const float*)d_in[8];
    const float* wq_w    = (const float*)d_in[9];
    const float* wq_b    = (const float*)d_in[10];
    const float* wk_w    = (const float*)d_in[11];
    const float* wk_b    = (const float*)d_in[12];
    const float* mlp2_w  = (const float*)d_in[13];
    const float* mlp2_b  = (const float*)d_in[14];
    float* ws  = (float*)d_ws;
    float* out = (float*)d_out;

    hipLaunchKernelGGL(prep_all, dim3(17), dim3(256), 0, stream,
                       fc1_w, fc2_w, bn_g, bn_b, bn_mean, bn_var,
                       wq_w, wq_b, wk_w, wk_b, mlp2_w, mlp2_b, ws, out);
    hipLaunchKernelGGL(main_mfma, dim3(512), dim3(256), 0, stream,
                       inputs, fc1_b, fc2_b, ws, out);
    hipLaunchKernelGGL(broadcast_out, dim3(2048), dim3(256), 0, stream, ws, out);
}